// Round 5
// baseline (218.847 us; speedup 1.0000x reference)
//
#include <hip/hip_runtime.h>
#include <hip/hip_fp16.h>
#include <hip/hip_cooperative_groups.h>
#include <math.h>

#define NN 20000
#define EE 320000
#define CIN 16
#define COUT 16
#define R2C 0.25f

// workspace layout:
//   cnts : int[NN] @ 0   (total incident edge count per node)
#define WS_NEED 81920

typedef _Float16 h2 __attribute__((ext_vector_type(2)));

#if defined(__has_builtin)
# if __has_builtin(__builtin_amdgcn_fdot2)
#  define HAS_FDOT2 1
# endif
#endif
#ifndef HAS_FDOT2
# define HAS_FDOT2 0
#endif

__device__ __forceinline__ h2 as_h2(unsigned int x) {
    union { unsigned int u; h2 h; } v; v.u = x; return v.h;
}
__device__ __forceinline__ h2 pk(float a, float b) {
    h2 r; r.x = (_Float16)a; r.y = (_Float16)b; return r;
}
__device__ __forceinline__ unsigned int pku(float a, float b) {
    __half2 h = __float22half2_rn(make_float2(a, b));
    return *(unsigned int*)&h;
}

// ---------------- edge-phase body (round-3 verbatim structure) ----------------
// Staging -> syncthreads -> 2 chunks of {ei load, cnt atomic, geometry, compaction loop}.
__device__ __forceinline__ void edge_body(const float* __restrict__ pos,
                                          const int* __restrict__ ei,
                                          const float* __restrict__ feat,
                                          const float* __restrict__ filt,
                                          float* __restrict__ out,
                                          int* __restrict__ cnts,
                                          uint4* __restrict__ sf,
                                          int bid) {
    {
        #pragma unroll
        for (int r = 0; r < 8; ++r) {
            int g = r * 256 + threadIdx.x;                 // granule id == LDS granule index
            const float* src = filt + (g >> 4) * 128 + (g & 15); // cell*256 + ci_hi*128 + o
            float s0 = src[0],  s1 = src[16],  s2 = src[32],  s3 = src[48];
            float s4 = src[64], s5 = src[80],  s6 = src[96],  s7 = src[112];
            uint4 v;
            v.x = pku(s0, s1); v.y = pku(s2, s3);
            v.z = pku(s4, s5); v.w = pku(s6, s7);
            sf[g] = v;
        }
    }
    __syncthreads();

    int lane = threadIdx.x & 63;
    int gid  = lane >> 4;        // 16-lane group id within wave
    int o    = lane & 15;        // output channel owned in compute phase
    int wv   = threadIdx.x >> 6;

    #pragma unroll
    for (int ch = 0; ch < 2; ++ch) {
        int e = bid * 512 + ch * 256 + wv * 64 + lane;

        int row = ei[e];
        int col = ei[EE + e];
        atomicAdd(&cnts[row], 1);     // fire-and-forget, mean divisor counts ALL edges

        float rx = pos[col*3+0] - pos[row*3+0];
        float ry = pos[col*3+1] - pos[row*3+1];
        float rz = pos[col*3+2] - pos[row*3+2];
        float d2 = rx*rx + ry*ry + rz*rz;
        bool valid = d2 < R2C;

        float win = 0.f, ad = 0.f, bd = 0.f, cd = 0.f;
        int colidx = 0;
        if (valid) {
            float u = 1.0f - d2 * 4.0f;           // 1 - d2/R^2
            win = u * u * u;
            // tanh(x)/x = 1 - u/3 + 2u^2/15 - 17u^3/315 + 62u^4/2835, u=x^2<=0.25 (err<1e-5)
            float s = 1.0f + d2*(-0.33333333f + d2*(0.13333333f + d2*(-0.05396825f + d2*0.02186949f)));
            float gx = (rx * s + 1.0f) * 1.5f;    // c-axis (k)
            float gy = (ry * s + 1.0f) * 1.5f;    // b-axis (j)
            float gz = (rz * s + 1.0f) * 1.5f;    // a-axis (i)
            float af = floorf(gz), bf = floorf(gy), cf = floorf(gx);
            int ia0 = min(max((int)af, 0), 2);    // gc in (0.8, 2.2) -> floor in {0,1,2}
            int jb0 = min(max((int)bf, 0), 2);
            int kc0 = min(max((int)cf, 0), 2);
            ad = gz - af; bd = gy - bf; cd = gx - cf;
            colidx = col | (ia0 << 20) | (jb0 << 24) | (kc0 << 28);
        }

        unsigned long long bal = __ballot(valid);
        int nv = __popcll(bal);
        unsigned long long m0 = bal;
        unsigned long long m1 = m0 & (m0 - 1);
        unsigned long long m2 = m1 & (m1 - 1);
        unsigned long long m3 = m2 & (m2 - 1);

        for (int k = 0; k < nv; k += 4) {
            unsigned long long mg = (gid == 0) ? m0 : (gid == 1) ? m1 : (gid == 2) ? m2 : m3;
            bool active = (k + gid) < nv;
            int src = active ? (int)__builtin_ctzll(mg) : 0;

            float win_s = __shfl(win, src, 64);
            float ad_s  = __shfl(ad,  src, 64);
            float bd_s  = __shfl(bd,  src, 64);
            float cd_s  = __shfl(cd,  src, 64);
            int   ci_s  = __shfl(colidx, src, 64);
            int   row_s = __shfl(row,    src, 64);

            m0 = m3 & (m3 - 1);
            m1 = m0 & (m0 - 1);
            m2 = m1 & (m1 - 1);
            m3 = m2 & (m2 - 1);

            if (active) {
                int col_s = ci_s & 0xFFFFF;
                int ia0 = (ci_s >> 20) & 3, jb0 = (ci_s >> 24) & 3, kc0 = (ci_s >> 28) & 3;

                const float4* fb = (const float4*)(feat + (size_t)col_s * 16);
                float4 fa = fb[0], fc = fb[1], fd = fb[2], fe = fb[3];

                float va0 = (1.f - ad_s) * win_s, va1 = ad_s * win_s;
                float vb0 = 1.f - bd_s, vb1 = bd_s;
                float vc0 = 1.f - cd_s, vc1 = cd_s;
                float p00 = va0*vb0, p01 = va0*vb1, p10 = va1*vb0, p11 = va1*vb1;
                float w8[8] = { p00*vc0, p00*vc1, p01*vc0, p01*vc1,
                                p10*vc0, p10*vc1, p11*vc0, p11*vc1 };

                int bi = ((ia0 * 16 + jb0 * 4 + kc0) << 5) + o;
                const int cofs[8] = {0, 32, 128, 160, 512, 544, 640, 672};

                float acc = 0.f;
#if HAS_FDOT2
                h2 ft0 = pk(fa.x, fa.y), ft1 = pk(fa.z, fa.w);
                h2 ft2 = pk(fc.x, fc.y), ft3 = pk(fc.z, fc.w);
                h2 ft4 = pk(fd.x, fd.y), ft5 = pk(fd.z, fd.w);
                h2 ft6 = pk(fe.x, fe.y), ft7 = pk(fe.z, fe.w);
                #pragma unroll
                for (int c = 0; c < 8; ++c) {
                    uint4 g0 = sf[bi + cofs[c]];
                    uint4 g1 = sf[bi + cofs[c] + 16];
                    float d = 0.f;
                    d = __builtin_amdgcn_fdot2(as_h2(g0.x), ft0, d, false);
                    d = __builtin_amdgcn_fdot2(as_h2(g0.y), ft1, d, false);
                    d = __builtin_amdgcn_fdot2(as_h2(g0.z), ft2, d, false);
                    d = __builtin_amdgcn_fdot2(as_h2(g0.w), ft3, d, false);
                    d = __builtin_amdgcn_fdot2(as_h2(g1.x), ft4, d, false);
                    d = __builtin_amdgcn_fdot2(as_h2(g1.y), ft5, d, false);
                    d = __builtin_amdgcn_fdot2(as_h2(g1.z), ft6, d, false);
                    d = __builtin_amdgcn_fdot2(as_h2(g1.w), ft7, d, false);
                    acc = fmaf(w8[c], d, acc);
                }
#else
                float ftf[16] = { fa.x, fa.y, fa.z, fa.w, fc.x, fc.y, fc.z, fc.w,
                                  fd.x, fd.y, fd.z, fd.w, fe.x, fe.y, fe.z, fe.w };
                #pragma unroll
                for (int c = 0; c < 8; ++c) {
                    uint4 g0 = sf[bi + cofs[c]];
                    uint4 g1 = sf[bi + cofs[c] + 16];
                    float d = 0.f;
                    h2 t;
                    t = as_h2(g0.x); d = fmaf((float)t.x, ftf[0],  d); d = fmaf((float)t.y, ftf[1],  d);
                    t = as_h2(g0.y); d = fmaf((float)t.x, ftf[2],  d); d = fmaf((float)t.y, ftf[3],  d);
                    t = as_h2(g0.z); d = fmaf((float)t.x, ftf[4],  d); d = fmaf((float)t.y, ftf[5],  d);
                    t = as_h2(g0.w); d = fmaf((float)t.x, ftf[6],  d); d = fmaf((float)t.y, ftf[7],  d);
                    t = as_h2(g1.x); d = fmaf((float)t.x, ftf[8],  d); d = fmaf((float)t.y, ftf[9],  d);
                    t = as_h2(g1.y); d = fmaf((float)t.x, ftf[10], d); d = fmaf((float)t.y, ftf[11], d);
                    t = as_h2(g1.z); d = fmaf((float)t.x, ftf[12], d); d = fmaf((float)t.y, ftf[13], d);
                    t = as_h2(g1.w); d = fmaf((float)t.x, ftf[14], d); d = fmaf((float)t.y, ftf[15], d);
                    acc = fmaf(w8[c], d, acc);
                }
#endif
                atomicAdd(out + (size_t)row_s * 16 + o, acc);
            }
        }
    }
}

// ---------------- fused cooperative kernel: zero -> edges -> divide ----------------
// 625 blocks x 256 threads; worst case 3 blocks/CU (LDS 96 KiB <= 160, 12 waves/CU <= 32).
__global__ __launch_bounds__(256, 3) void k_fused(const float* __restrict__ pos,
                                                  const int* __restrict__ ei,
                                                  const float* __restrict__ feat,
                                                  const float* __restrict__ filt,
                                                  float* __restrict__ out,
                                                  int* __restrict__ cnts) {
    __shared__ uint4 sf[2048];   // 32 KiB fp16 filters, granule = cell*32 + ci_hi*16 + o
    cooperative_groups::grid_group grid = cooperative_groups::this_grid();

    int t = blockIdx.x * 256 + threadIdx.x;   // 0 .. 159999

    // phase 0: zero out (float2 per thread) + cnts
    ((float2*)out)[t] = make_float2(0.f, 0.f);
    if (t < NN) cnts[t] = 0;

    grid.sync();

    // phase 1: edge conv (round-3 body)
    edge_body(pos, ei, feat, filt, out, cnts, sf, blockIdx.x);

    grid.sync();

    // phase 2: divide by all-edge count (same float2 ownership as phase 0)
    {
        int c = cnts[t >> 3];
        float inv = (c > 1) ? 1.0f / (float)c : 1.0f;
        float2 v = ((float2*)out)[t];
        ((float2*)out)[t] = make_float2(v.x * inv, v.y * inv);
    }
}

// ---------------- standalone 3-dispatch path (fallback if cooperative refused) ----------------
__global__ __launch_bounds__(256) void k_zero(float* __restrict__ out, int* __restrict__ cnt) {
    int i = blockIdx.x * 256 + threadIdx.x;
    if (i < NN * COUT) out[i] = 0.0f;
    if (i < NN) cnt[i] = 0;
}

__global__ __launch_bounds__(256) void k_edge(const float* __restrict__ pos,
                                              const int* __restrict__ ei,
                                              const float* __restrict__ feat,
                                              const float* __restrict__ filt,
                                              float* __restrict__ out,
                                              int* __restrict__ cnts) {
    __shared__ uint4 sf[2048];
    edge_body(pos, ei, feat, filt, out, cnts, sf, blockIdx.x);
}

__global__ __launch_bounds__(256) void k_div(float* __restrict__ out, const int* __restrict__ cnt) {
    int i = blockIdx.x * 256 + threadIdx.x;
    if (i >= NN * COUT) return;
    int c = cnt[i >> 4];
    float denom = (c > 1) ? (float)c : 1.0f;
    out[i] = out[i] / denom;
}

// ---------------- geometry helper (no-ws fallback path) ----------------
__device__ __forceinline__ bool edge_geom(const float* __restrict__ pos, int row, int col,
                                          float& win,
                                          int ia[2], int jb[2], int kc[2],
                                          float wa[2], float wb[2], float wc[2]) {
    float rx = pos[col*3+0] - pos[row*3+0];
    float ry = pos[col*3+1] - pos[row*3+1];
    float rz = pos[col*3+2] - pos[row*3+2];
    float d2 = rx*rx + ry*ry + rz*rz;
    if (!(d2 < R2C)) return false;
    float u = 1.0f - d2 / R2C;
    win = u * u * u;
    float nr = sqrtf(d2);
    float s  = tanhf(nr) / (nr + 1e-8f);
    float gx = (rx * s + 1.0f) * 1.5f;
    float gy = (ry * s + 1.0f) * 1.5f;
    float gz = (rz * s + 1.0f) * 1.5f;
    float af = floorf(gz), bf = floorf(gy), cf = floorf(gx);
    int ia0 = min(max((int)af, 0), 3);
    int ib0 = min(max((int)bf, 0), 3);
    int ic0 = min(max((int)cf, 0), 3);
    ia[0] = ia0; ia[1] = min(ia0 + 1, 3);
    jb[0] = ib0; jb[1] = min(ib0 + 1, 3);
    kc[0] = ic0; kc[1] = min(ic0 + 1, 3);
    float ad = gz - af, bd = gy - bf, cd = gx - cf;
    wa[0] = 1.0f - ad; wa[1] = ad;
    wb[0] = 1.0f - bd; wb[1] = bd;
    wc[0] = 1.0f - cd; wc[1] = cd;
    return true;
}

__global__ __launch_bounds__(256) void k_edge_direct(const float* __restrict__ pos,
                                                     const float* __restrict__ feat,
                                                     const float* __restrict__ filt,
                                                     const int* __restrict__ ei,
                                                     float* __restrict__ out,
                                                     int* __restrict__ cnt) {
    int e = blockIdx.x * 256 + threadIdx.x;
    if (e >= EE) return;
    int row = ei[e];
    int col = ei[EE + e];
    atomicAdd(&cnt[row], 1);

    float win;
    int ia[2], jb[2], kc[2];
    float wa[2], wb[2], wc[2];
    if (!edge_geom(pos, row, col, win, ia, jb, kc, wa, wb, wc)) return;

    float fv[16];
    const float4* fp = (const float4*)(feat + (size_t)col * 16);
    float4 f0 = fp[0], f1 = fp[1], f2 = fp[2], f3 = fp[3];
    fv[0]=f0.x; fv[1]=f0.y; fv[2]=f0.z; fv[3]=f0.w;
    fv[4]=f1.x; fv[5]=f1.y; fv[6]=f1.z; fv[7]=f1.w;
    fv[8]=f2.x; fv[9]=f2.y; fv[10]=f2.z; fv[11]=f2.w;
    fv[12]=f3.x; fv[13]=f3.y; fv[14]=f3.z; fv[15]=f3.w;

    float4 a0 = make_float4(0.f,0.f,0.f,0.f);
    float4 a1 = a0, a2 = a0, a3 = a0;
    for (int da = 0; da < 2; ++da)
    for (int db = 0; db < 2; ++db)
    for (int dc = 0; dc < 2; ++dc) {
        float w = wa[da] * wb[db] * wc[dc] * win;
        const float* fb = filt + (size_t)(ia[da]*16 + jb[db]*4 + kc[dc]) * 256;
        #pragma unroll
        for (int ci = 0; ci < 16; ++ci) {
            float c = w * fv[ci];
            const float4* r4 = (const float4*)(fb + ci * 16);
            float4 w0 = r4[0], w1 = r4[1], w2 = r4[2], w3 = r4[3];
            a0.x = fmaf(c, w0.x, a0.x); a0.y = fmaf(c, w0.y, a0.y);
            a0.z = fmaf(c, w0.z, a0.z); a0.w = fmaf(c, w0.w, a0.w);
            a1.x = fmaf(c, w1.x, a1.x); a1.y = fmaf(c, w1.y, a1.y);
            a1.z = fmaf(c, w1.z, a1.z); a1.w = fmaf(c, w1.w, a1.w);
            a2.x = fmaf(c, w2.x, a2.x); a2.y = fmaf(c, w2.y, a2.y);
            a2.z = fmaf(c, w2.z, a2.z); a2.w = fmaf(c, w2.w, a2.w);
            a3.x = fmaf(c, w3.x, a3.x); a3.y = fmaf(c, w3.y, a3.y);
            a3.z = fmaf(c, w3.z, a3.z); a3.w = fmaf(c, w3.w, a3.w);
        }
    }
    float* op = out + (size_t)row * 16;
    atomicAdd(op+0,  a0.x); atomicAdd(op+1,  a0.y); atomicAdd(op+2,  a0.z); atomicAdd(op+3,  a0.w);
    atomicAdd(op+4,  a1.x); atomicAdd(op+5,  a1.y); atomicAdd(op+6,  a1.z); atomicAdd(op+7,  a1.w);
    atomicAdd(op+8,  a2.x); atomicAdd(op+9,  a2.y); atomicAdd(op+10, a2.z); atomicAdd(op+11, a2.w);
    atomicAdd(op+12, a3.x); atomicAdd(op+13, a3.y); atomicAdd(op+14, a3.z); atomicAdd(op+15, a3.w);
}

extern "C" void kernel_launch(void* const* d_in, const int* in_sizes, int n_in,
                              void* d_out, int out_size, void* d_ws, size_t ws_size,
                              hipStream_t stream) {
    const float* pos  = (const float*)d_in[0];
    const float* feat = (const float*)d_in[1];
    const float* filt = (const float*)d_in[2];
    const int*   ei   = (const int*)d_in[3];
    float* out = (float*)d_out;

    int* cnts = (int*)d_ws;

    if (ws_size >= WS_NEED) {
        void* args[] = { (void*)&pos, (void*)&ei, (void*)&feat, (void*)&filt,
                         (void*)&out, (void*)&cnts };
        hipError_t err = hipLaunchCooperativeKernel((void*)k_fused, dim3(625), dim3(256),
                                                    args, 0, stream);
        if (err == hipSuccess) return;
        // cooperative refused -> 3-dispatch path (round-3 structure)
        k_zero<<<(NN * COUT + 255) / 256, 256, 0, stream>>>(out, cnts);
        k_edge<<<625, 256, 0, stream>>>(pos, ei, feat, filt, out, cnts);
        k_div<<<(NN * COUT + 255) / 256, 256, 0, stream>>>(out, cnts);
    } else {
        k_zero<<<(NN * COUT + 255) / 256, 256, 0, stream>>>(out, cnts);
        k_edge_direct<<<(EE + 255) / 256, 256, 0, stream>>>(pos, feat, filt, ei, out, cnts);
        k_div<<<(NN * COUT + 255) / 256, 256, 0, stream>>>(out, cnts);
    }
}

// Round 6
// 91.273 us; speedup vs baseline: 2.3977x; 2.3977x over previous
//
#include <hip/hip_runtime.h>
#include <hip/hip_fp16.h>
#include <math.h>

#define NN 20000
#define EE 320000
#define CIN 16
#define COUT 16
#define R2C 0.25f

// workspace layout:
//   cnts : int[NN] @ 0   (total incident edge count per node)
#define WS_NEED 81920

typedef _Float16 h2 __attribute__((ext_vector_type(2)));

#if defined(__has_builtin)
# if __has_builtin(__builtin_amdgcn_fdot2)
#  define HAS_FDOT2 1
# endif
#endif
#ifndef HAS_FDOT2
# define HAS_FDOT2 0
#endif

__device__ __forceinline__ h2 as_h2(unsigned int x) {
    union { unsigned int u; h2 h; } v; v.u = x; return v.h;
}
__device__ __forceinline__ h2 pk(float a, float b) {
    h2 r; r.x = (_Float16)a; r.y = (_Float16)b; return r;
}
__device__ __forceinline__ unsigned int pku(float a, float b) {
    __half2 h = __float22half2_rn(make_float2(a, b));
    return *(unsigned int*)&h;
}

// ---------------- zero out + counters ----------------
__global__ __launch_bounds__(256) void k_zero(float* __restrict__ out, int* __restrict__ cnt) {
    int i = blockIdx.x * 256 + threadIdx.x;
    if (i < NN * COUT) out[i] = 0.0f;
    if (i < NN) cnt[i] = 0;
}

// ---------------- fused edge kernel: geometry + compaction + LDS-filter conv + atomic out ----------------
// 625 blocks x 2 chunks x 256 edges = EE exactly.
// Staging: per-granule gather (coalesced across 16-lane o-groups), one ds_write_b128 per granule.
// LDS layout: granule(16B) = cell*32 + ci_hi*16 + o, holding filt[cell][ci_hi*8 .. +8][o] as 8 halves.
__global__ __launch_bounds__(256) void k_edge(const float* __restrict__ pos,
                                              const int* __restrict__ ei,
                                              const float* __restrict__ feat,
                                              const float* __restrict__ filt,
                                              float* __restrict__ out,
                                              int* __restrict__ cnts) {
    __shared__ uint4 sf[2048];   // 32 KiB fp16 filters
    {
        #pragma unroll
        for (int r = 0; r < 8; ++r) {
            int g = r * 256 + threadIdx.x;                 // granule id == LDS granule index
            const float* src = filt + (g >> 4) * 128 + (g & 15); // cell*256 + ci_hi*128 + o
            float s0 = src[0],  s1 = src[16],  s2 = src[32],  s3 = src[48];
            float s4 = src[64], s5 = src[80],  s6 = src[96],  s7 = src[112];
            uint4 v;
            v.x = pku(s0, s1); v.y = pku(s2, s3);
            v.z = pku(s4, s5); v.w = pku(s6, s7);
            sf[g] = v;
        }
    }
    __syncthreads();

    int lane = threadIdx.x & 63;
    int gid  = lane >> 4;        // 16-lane group id within wave
    int o    = lane & 15;        // output channel owned in compute phase
    int wv   = threadIdx.x >> 6;

    #pragma unroll
    for (int ch = 0; ch < 2; ++ch) {
        int e = blockIdx.x * 512 + ch * 256 + wv * 64 + lane;

        int row = ei[e];
        int col = ei[EE + e];
        atomicAdd(&cnts[row], 1);     // fire-and-forget, mean divisor counts ALL edges

        float rx = pos[col*3+0] - pos[row*3+0];
        float ry = pos[col*3+1] - pos[row*3+1];
        float rz = pos[col*3+2] - pos[row*3+2];
        float d2 = rx*rx + ry*ry + rz*rz;
        bool valid = d2 < R2C;

        float win = 0.f, ad = 0.f, bd = 0.f, cd = 0.f;
        int colidx = 0;
        if (valid) {
            float u = 1.0f - d2 * 4.0f;           // 1 - d2/R^2
            win = u * u * u;
            // tanh(x)/x = 1 - u/3 + 2u^2/15 - 17u^3/315 + 62u^4/2835, u=x^2<=0.25 (err<1e-5)
            float s = 1.0f + d2*(-0.33333333f + d2*(0.13333333f + d2*(-0.05396825f + d2*0.02186949f)));
            float gx = (rx * s + 1.0f) * 1.5f;    // c-axis (k)
            float gy = (ry * s + 1.0f) * 1.5f;    // b-axis (j)
            float gz = (rz * s + 1.0f) * 1.5f;    // a-axis (i)
            float af = floorf(gz), bf = floorf(gy), cf = floorf(gx);
            int ia0 = min(max((int)af, 0), 2);    // gc in (0.8, 2.2) -> floor in {0,1,2}
            int jb0 = min(max((int)bf, 0), 2);
            int kc0 = min(max((int)cf, 0), 2);
            ad = gz - af; bd = gy - bf; cd = gx - cf;
            colidx = col | (ia0 << 20) | (jb0 << 24) | (kc0 << 28);
        }

        unsigned long long bal = __ballot(valid);
        int nv = __popcll(bal);
        unsigned long long m0 = bal;
        unsigned long long m1 = m0 & (m0 - 1);
        unsigned long long m2 = m1 & (m1 - 1);
        unsigned long long m3 = m2 & (m2 - 1);

        for (int k = 0; k < nv; k += 4) {
            unsigned long long mg = (gid == 0) ? m0 : (gid == 1) ? m1 : (gid == 2) ? m2 : m3;
            bool active = (k + gid) < nv;
            int src = active ? (int)__builtin_ctzll(mg) : 0;

            float win_s = __shfl(win, src, 64);
            float ad_s  = __shfl(ad,  src, 64);
            float bd_s  = __shfl(bd,  src, 64);
            float cd_s  = __shfl(cd,  src, 64);
            int   ci_s  = __shfl(colidx, src, 64);
            int   row_s = __shfl(row,    src, 64);

            m0 = m3 & (m3 - 1);
            m1 = m0 & (m0 - 1);
            m2 = m1 & (m1 - 1);
            m3 = m2 & (m2 - 1);

            if (active) {
                int col_s = ci_s & 0xFFFFF;
                int ia0 = (ci_s >> 20) & 3, jb0 = (ci_s >> 24) & 3, kc0 = (ci_s >> 28) & 3;

                const float4* fb = (const float4*)(feat + (size_t)col_s * 16);
                float4 fa = fb[0], fc = fb[1], fd = fb[2], fe = fb[3];

                float va0 = (1.f - ad_s) * win_s, va1 = ad_s * win_s;
                float vb0 = 1.f - bd_s, vb1 = bd_s;
                float vc0 = 1.f - cd_s, vc1 = cd_s;
                float p00 = va0*vb0, p01 = va0*vb1, p10 = va1*vb0, p11 = va1*vb1;
                float w8[8] = { p00*vc0, p00*vc1, p01*vc0, p01*vc1,
                                p10*vc0, p10*vc1, p11*vc0, p11*vc1 };

                int bi = ((ia0 * 16 + jb0 * 4 + kc0) << 5) + o;
                const int cofs[8] = {0, 32, 128, 160, 512, 544, 640, 672};

                float acc = 0.f;
#if HAS_FDOT2
                h2 ft0 = pk(fa.x, fa.y), ft1 = pk(fa.z, fa.w);
                h2 ft2 = pk(fc.x, fc.y), ft3 = pk(fc.z, fc.w);
                h2 ft4 = pk(fd.x, fd.y), ft5 = pk(fd.z, fd.w);
                h2 ft6 = pk(fe.x, fe.y), ft7 = pk(fe.z, fe.w);
                #pragma unroll
                for (int c = 0; c < 8; ++c) {
                    uint4 g0 = sf[bi + cofs[c]];
                    uint4 g1 = sf[bi + cofs[c] + 16];
                    float d = 0.f;
                    d = __builtin_amdgcn_fdot2(as_h2(g0.x), ft0, d, false);
                    d = __builtin_amdgcn_fdot2(as_h2(g0.y), ft1, d, false);
                    d = __builtin_amdgcn_fdot2(as_h2(g0.z), ft2, d, false);
                    d = __builtin_amdgcn_fdot2(as_h2(g0.w), ft3, d, false);
                    d = __builtin_amdgcn_fdot2(as_h2(g1.x), ft4, d, false);
                    d = __builtin_amdgcn_fdot2(as_h2(g1.y), ft5, d, false);
                    d = __builtin_amdgcn_fdot2(as_h2(g1.z), ft6, d, false);
                    d = __builtin_amdgcn_fdot2(as_h2(g1.w), ft7, d, false);
                    acc = fmaf(w8[c], d, acc);
                }
#else
                float ftf[16] = { fa.x, fa.y, fa.z, fa.w, fc.x, fc.y, fc.z, fc.w,
                                  fd.x, fd.y, fd.z, fd.w, fe.x, fe.y, fe.z, fe.w };
                #pragma unroll
                for (int c = 0; c < 8; ++c) {
                    uint4 g0 = sf[bi + cofs[c]];
                    uint4 g1 = sf[bi + cofs[c] + 16];
                    float d = 0.f;
                    h2 t;
                    t = as_h2(g0.x); d = fmaf((float)t.x, ftf[0],  d); d = fmaf((float)t.y, ftf[1],  d);
                    t = as_h2(g0.y); d = fmaf((float)t.x, ftf[2],  d); d = fmaf((float)t.y, ftf[3],  d);
                    t = as_h2(g0.z); d = fmaf((float)t.x, ftf[4],  d); d = fmaf((float)t.y, ftf[5],  d);
                    t = as_h2(g0.w); d = fmaf((float)t.x, ftf[6],  d); d = fmaf((float)t.y, ftf[7],  d);
                    t = as_h2(g1.x); d = fmaf((float)t.x, ftf[8],  d); d = fmaf((float)t.y, ftf[9],  d);
                    t = as_h2(g1.y); d = fmaf((float)t.x, ftf[10], d); d = fmaf((float)t.y, ftf[11], d);
                    t = as_h2(g1.z); d = fmaf((float)t.x, ftf[12], d); d = fmaf((float)t.y, ftf[13], d);
                    t = as_h2(g1.w); d = fmaf((float)t.x, ftf[14], d); d = fmaf((float)t.y, ftf[15], d);
                    acc = fmaf(w8[c], d, acc);
                }
#endif
                atomicAdd(out + (size_t)row_s * 16 + o, acc);
            }
        }
    }
}

// ---------------- divide by all-edge count ----------------
__global__ __launch_bounds__(256) void k_div(float* __restrict__ out, const int* __restrict__ cnt) {
    int i = blockIdx.x * 256 + threadIdx.x;
    if (i >= NN * COUT) return;
    int c = cnt[i >> 4];
    float denom = (c > 1) ? (float)c : 1.0f;
    out[i] = out[i] / denom;
}

// ---------------- geometry helper (fallback path) ----------------
__device__ __forceinline__ bool edge_geom(const float* __restrict__ pos, int row, int col,
                                          float& win,
                                          int ia[2], int jb[2], int kc[2],
                                          float wa[2], float wb[2], float wc[2]) {
    float rx = pos[col*3+0] - pos[row*3+0];
    float ry = pos[col*3+1] - pos[row*3+1];
    float rz = pos[col*3+2] - pos[row*3+2];
    float d2 = rx*rx + ry*ry + rz*rz;
    if (!(d2 < R2C)) return false;
    float u = 1.0f - d2 / R2C;
    win = u * u * u;
    float nr = sqrtf(d2);
    float s  = tanhf(nr) / (nr + 1e-8f);
    float gx = (rx * s + 1.0f) * 1.5f;
    float gy = (ry * s + 1.0f) * 1.5f;
    float gz = (rz * s + 1.0f) * 1.5f;
    float af = floorf(gz), bf = floorf(gy), cf = floorf(gx);
    int ia0 = min(max((int)af, 0), 3);
    int ib0 = min(max((int)bf, 0), 3);
    int ic0 = min(max((int)cf, 0), 3);
    ia[0] = ia0; ia[1] = min(ia0 + 1, 3);
    jb[0] = ib0; jb[1] = min(ib0 + 1, 3);
    kc[0] = ic0; kc[1] = min(ic0 + 1, 3);
    float ad = gz - af, bd = gy - bf, cd = gx - cf;
    wa[0] = 1.0f - ad; wa[1] = ad;
    wb[0] = 1.0f - bd; wb[1] = bd;
    wc[0] = 1.0f - cd; wc[1] = cd;
    return true;
}

// ---------------- fallback: direct edge kernel, filters from global ----------------
__global__ __launch_bounds__(256) void k_edge_direct(const float* __restrict__ pos,
                                                     const float* __restrict__ feat,
                                                     const float* __restrict__ filt,
                                                     const int* __restrict__ ei,
                                                     float* __restrict__ out,
                                                     int* __restrict__ cnt) {
    int e = blockIdx.x * 256 + threadIdx.x;
    if (e >= EE) return;
    int row = ei[e];
    int col = ei[EE + e];
    atomicAdd(&cnt[row], 1);

    float win;
    int ia[2], jb[2], kc[2];
    float wa[2], wb[2], wc[2];
    if (!edge_geom(pos, row, col, win, ia, jb, kc, wa, wb, wc)) return;

    float fv[16];
    const float4* fp = (const float4*)(feat + (size_t)col * 16);
    float4 f0 = fp[0], f1 = fp[1], f2 = fp[2], f3 = fp[3];
    fv[0]=f0.x; fv[1]=f0.y; fv[2]=f0.z; fv[3]=f0.w;
    fv[4]=f1.x; fv[5]=f1.y; fv[6]=f1.z; fv[7]=f1.w;
    fv[8]=f2.x; fv[9]=f2.y; fv[10]=f2.z; fv[11]=f2.w;
    fv[12]=f3.x; fv[13]=f3.y; fv[14]=f3.z; fv[15]=f3.w;

    float4 a0 = make_float4(0.f,0.f,0.f,0.f);
    float4 a1 = a0, a2 = a0, a3 = a0;
    for (int da = 0; da < 2; ++da)
    for (int db = 0; db < 2; ++db)
    for (int dc = 0; dc < 2; ++dc) {
        float w = wa[da] * wb[db] * wc[dc] * win;
        const float* fb = filt + (size_t)(ia[da]*16 + jb[db]*4 + kc[dc]) * 256;
        #pragma unroll
        for (int ci = 0; ci < 16; ++ci) {
            float c = w * fv[ci];
            const float4* r4 = (const float4*)(fb + ci * 16);
            float4 w0 = r4[0], w1 = r4[1], w2 = r4[2], w3 = r4[3];
            a0.x = fmaf(c, w0.x, a0.x); a0.y = fmaf(c, w0.y, a0.y);
            a0.z = fmaf(c, w0.z, a0.z); a0.w = fmaf(c, w0.w, a0.w);
            a1.x = fmaf(c, w1.x, a1.x); a1.y = fmaf(c, w1.y, a1.y);
            a1.z = fmaf(c, w1.z, a1.z); a1.w = fmaf(c, w1.w, a1.w);
            a2.x = fmaf(c, w2.x, a2.x); a2.y = fmaf(c, w2.y, a2.y);
            a2.z = fmaf(c, w2.z, a2.z); a2.w = fmaf(c, w2.w, a2.w);
            a3.x = fmaf(c, w3.x, a3.x); a3.y = fmaf(c, w3.y, a3.y);
            a3.w = fmaf(c, w3.w, a3.w); a3.z = fmaf(c, w3.z, a3.z);
        }
    }
    float* op = out + (size_t)row * 16;
    atomicAdd(op+0,  a0.x); atomicAdd(op+1,  a0.y); atomicAdd(op+2,  a0.z); atomicAdd(op+3,  a0.w);
    atomicAdd(op+4,  a1.x); atomicAdd(op+5,  a1.y); atomicAdd(op+6,  a1.z); atomicAdd(op+7,  a1.w);
    atomicAdd(op+8,  a2.x); atomicAdd(op+9,  a2.y); atomicAdd(op+10, a2.z); atomicAdd(op+11, a2.w);
    atomicAdd(op+12, a3.x); atomicAdd(op+13, a3.y); atomicAdd(op+14, a3.z); atomicAdd(op+15, a3.w);
}

extern "C" void kernel_launch(void* const* d_in, const int* in_sizes, int n_in,
                              void* d_out, int out_size, void* d_ws, size_t ws_size,
                              hipStream_t stream) {
    const float* pos  = (const float*)d_in[0];
    const float* feat = (const float*)d_in[1];
    const float* filt = (const float*)d_in[2];
    const int*   ei   = (const int*)d_in[3];
    float* out = (float*)d_out;

    int* cnts = (int*)d_ws;

    k_zero<<<(NN * COUT + 255) / 256, 256, 0, stream>>>(out, cnts);
    if (ws_size >= WS_NEED) {
        k_edge<<<625, 256, 0, stream>>>(pos, ei, feat, filt, out, cnts);
    } else {
        k_edge_direct<<<(EE + 255) / 256, 256, 0, stream>>>(pos, feat, filt, ei, out, cnts);
    }
    k_div<<<(NN * COUT + 255) / 256, 256, 0, stream>>>(out, cnts);
}